// Round 2
// baseline (96.404 us; speedup 1.0000x reference)
//
#include <hip/hip_runtime.h>

#define NG 512
#define NPX 262144
#define BLOCK 256
#define GTILE 8   // Gaussians per register tile

#if __has_builtin(__builtin_amdgcn_exp2f)
  #define KSCALE 0.72134752044448170368f   /* 0.5 * log2(e) */
  #define EXPNEG(w) __builtin_amdgcn_exp2f(-(w))
#else
  #define KSCALE 0.5f
  #define EXPNEG(w) __expf(-(w))
#endif

// ---------------------------------------------------------------------------
// Prep kernel: fold rotation/scale/mean/alpha into 6 constants per Gaussian.
//   ga[n] = (p00, p01, -uoff, alpha)      (float4, 8 KB total)
//   gb[n] = (p11, -voff)                  (float2, 4 KB total)
// k*q = (p00*x + p01*y - uoff)^2 + (p11*y - voff)^2, k = 0.5*log2(e)
// ---------------------------------------------------------------------------
__global__ void gsplat_prep(const float* __restrict__ alphas,
                            const float* __restrict__ means,
                            const float* __restrict__ rotations,
                            const float* __restrict__ scales,
                            float4* __restrict__ ga,
                            float2* __restrict__ gb)
{
    int n = blockIdx.x * blockDim.x + threadIdx.x;
    if (n >= NG) return;

    float rot = rotations[n];
    float sth, cth;
    sincosf(rot, &sth, &cth);
    float s0 = scales[2 * n + 0];
    float s1 = scales[2 * n + 1];
    float r00 = s0 * cth, r01 = -s1 * sth;
    float r10 = s0 * sth, r11 =  s1 * cth;
    float Ar = r00 * r00 + r01 * r01;
    float Br = r00 * r10 + r01 * r11;
    float Dr = r10 * r10 + r11 * r11;
    float det = Ar * Dr - Br * Br;
    float kc00 =  KSCALE * Dr / det;
    float kc01 = -KSCALE * Br / det;
    float p00 = sqrtf(kc00);
    float p01 = kc01 / p00;
    float p11 = sqrtf(KSCALE / Dr);
    float mx = means[2 * n + 0];
    float my = means[2 * n + 1];
    float nuoff = -(p00 * mx + p01 * my);
    float nvoff = -(p11 * my);

    ga[n] = make_float4(p00, p01, nuoff, alphas[n]);
    gb[n] = make_float2(p11, nvoff);
}

// ---------------------------------------------------------------------------
// Main kernel: one pixel per thread. Gaussian constants are read with
// wave-uniform addresses from global memory -> compiler selects s_load into
// SGPRs (scalar cache; 12 KB total). No LDS, no DS-pipe traffic at all.
// ---------------------------------------------------------------------------
__global__ __launch_bounds__(BLOCK)
void gsplat_main(const float* __restrict__ x,
                 const float4* __restrict__ ga,
                 const float2* __restrict__ gb,
                 float* __restrict__ out)
{
    int tid = blockIdx.x * BLOCK + threadIdx.x;
    float2 xv = ((const float2*)x)[tid];   // one pixel per thread
    float x0 = xv.x, y0 = xv.y;

    float acc0 = 0.0f, acc1 = 0.0f;
    for (int t = 0; t < NG; t += GTILE) {
        // batched uniform loads -> SGPR tile (s_load_dwordx4/x8 expected)
        float4 a[GTILE];
        float2 b[GTILE];
        #pragma unroll
        for (int j = 0; j < GTILE; ++j) {
            a[j] = ga[t + j];
            b[j] = gb[t + j];
        }
        #pragma unroll
        for (int j = 0; j < GTILE; ++j) {
            float u = fmaf(a[j].x, x0, fmaf(a[j].y, y0, a[j].z));
            float v = fmaf(b[j].x, y0, b[j].y);
            float w = fmaf(v, v, u * u);
            float e = EXPNEG(w);
            if (j & 1) acc1 = fmaf(a[j].w, e, acc1);
            else       acc0 = fmaf(a[j].w, e, acc0);
        }
    }

    out[tid] = acc0 + acc1;
}

extern "C" void kernel_launch(void* const* d_in, const int* in_sizes, int n_in,
                              void* d_out, int out_size, void* d_ws, size_t ws_size,
                              hipStream_t stream) {
    const float* x         = (const float*)d_in[0];
    const float* alphas    = (const float*)d_in[1];
    const float* means     = (const float*)d_in[2];
    const float* rotations = (const float*)d_in[3];
    const float* scales    = (const float*)d_in[4];
    float* out = (float*)d_out;

    float4* ga = (float4*)d_ws;                          // 512 * 16 B = 8 KB
    float2* gb = (float2*)((char*)d_ws + NG * 16);       // 512 *  8 B = 4 KB

    gsplat_prep<<<(NG + 255) / 256, 256, 0, stream>>>(alphas, means, rotations, scales, ga, gb);

    int grid = NPX / BLOCK;  // 1024 blocks -> 4 blocks/CU, 16 waves/CU
    gsplat_main<<<grid, BLOCK, 0, stream>>>(x, ga, gb, out);
}